// Round 1
// baseline (414.982 us; speedup 1.0000x reference)
//
#include <hip/hip_runtime.h>

// FloodPath R4: barrier-free wave-autonomous flood.
//   K1 (pack): unchanged — stream float2 [H][W][2] -> occ/flood bit planes.
//   K2 (flood): each WAVE owns a 64x64 halo'd window fully in registers:
//     lane = row (64 rows), one u64 = 64 cols. 16 dilation steps are pure
//     register ops + __shfl up/down (no barriers, no LDS in the loop).
//     Interior 32x32 exact after 16 steps (halo 16 on all sides).
//     5-plane bit-sliced counters in registers; one 7 KiB LDS transpose
//     for the coalesced float3 output sweep. ONE __syncthreads total.
// Rationale: R3's flood was phase/latency-bound (16 barriered LDS steps,
// each only ~30 VALU cycles). This makes flood a pure write stream.

typedef unsigned long long u64;

#define HH 4096
#define WW 4096
#define WPR 64            // u64 words per image row
#define NSTEPS 16
#define HALO 16
#define IT 32             // interior tile side per wave (64x64 window)

// ---------------- Kernel 1: bitpack ----------------
__global__ __launch_bounds__(256) void pack_kernel(
    const float* __restrict__ flood_input,
    u64* __restrict__ occP, u64* __restrict__ flP)
{
    const int lane = threadIdx.x & 63;
    const int wv   = threadIdx.x >> 6;
    const int r    = blockIdx.x;                  // one image row per block
#pragma unroll
    for (int b = 0; b < 2; ++b) {
        float vx[8], vy[8];
#pragma unroll
        for (int j = 0; j < 8; ++j) {
            const int w = wv * 16 + b * 8 + j;
            const float2 v = *(const float2*)(flood_input +
                                ((size_t)r * WW + (w << 6) + lane) * 2);
            vx[j] = v.x; vy[j] = v.y;
        }
#pragma unroll
        for (int j = 0; j < 8; ++j) {
            const int w = wv * 16 + b * 8 + j;
            const u64 om = __ballot(vx[j] > 0.5f);
            const u64 fm = __ballot(vy[j] > 0.5f);
            if (lane == 0) {
                occP[(size_t)r * WPR + w] = om;
                flP [(size_t)r * WPR + w] = fm;
            }
        }
    }
}

// ---------------- Kernel 2: flood + count + output ----------------
__global__ __launch_bounds__(256, 8) void flood_kernel(
    const u64* __restrict__ occP, const u64* __restrict__ flP,
    const float* __restrict__ flood_count,
    float* __restrict__ out)
{
    // [wave][interior row][occ, f, c0..c4] — 7168 B
    __shared__ u64 plane[4][IT][7];

    const int tid  = threadIdx.x;
    const int lane = tid & 63;
    const int wv   = tid >> 6;

    const int tile_r0 = blockIdx.y * IT;                 // 0..4064
    const int tile_c0 = blockIdx.x * (4 * IT) + wv * IT; // grid.x = 32

    // ---- Stage window: rows tile_r0-16+lane, cols tile_c0-16 .. +47.
    const int gr  = tile_r0 - HALO + lane;
    const bool rin = (gr >= 0) & (gr < HH);
    const int s   = tile_c0 - HALO;              // >= -16
    const int q0  = ((s + 64) >> 6) - 1;         // floor(s/64)
    const int sh  = s - (q0 << 6);               // 16 or 48

    const size_t base = (size_t)(rin ? gr : 0) * WPR;
    const int qa = min(max(q0, 0), WPR - 1);
    const int qb = min(max(q0 + 1, 0), WPR - 1);
    u64 o0 = occP[base + qa], o1 = occP[base + qb];
    u64 f0 = flP [base + qa], f1 = flP [base + qb];
    const bool va = rin & (q0 >= 0);
    const bool vb = rin & (q0 + 1 < WPR);
    if (!va) { o0 = ~0ull; f0 = 0ull; }          // OOB => wall, no flood
    if (!vb) { o1 = ~0ull; f1 = 0ull; }
    const u64 occ = (o0 >> sh) | (sh ? (o1 << (64 - sh)) : 0ull);
    u64       f   = (f0 >> sh) | (sh ? (f1 << (64 - sh)) : 0ull);

    // ---- 16 dilation steps, fully in registers. No barriers.
    const u64 nocc = ~occ;
    u64 c0 = 0, c1 = 0, c2 = 0, c3 = 0, c4 = 0;
#pragma unroll
    for (int it = 0; it < NSTEPS; ++it) {
        u64 up = __shfl_up(f, 1);
        u64 dn = __shfl_down(f, 1);
        if (lane == 0)  up = 0ull;
        if (lane == 63) dn = 0ull;
        f = nocc & (f | (f << 1) | (f >> 1) | up | dn);
        u64 c = f, t;
        t = c0; c0 = t ^ c; c = t & c;
        t = c1; c1 = t ^ c; c = t & c;
        t = c2; c2 = t ^ c; c = t & c;
        t = c3; c3 = t ^ c; c = t & c;
        c4 ^= c;                                 // max 16: no carry out
    }

    // ---- Transpose interior rows through LDS for the output sweep.
    if (lane >= HALO && lane < HALO + IT) {
        u64* p = plane[wv][lane - HALO];
        p[0] = occ; p[1] = f;
        p[2] = c0; p[3] = c1; p[4] = c2; p[5] = c3; p[6] = c4;
    }
    __syncthreads();   // cheap: one barrier total; guarantees LDS visibility

    // ---- Output: 2 rows per iteration (half-wave each), float3 stores.
    const int half = lane >> 5;                  // 0 or 1
    const int col  = lane & 31;
    const int gc   = tile_c0 + col;
    const int bit  = HALO + col;                 // 16..47
#pragma unroll 4
    for (int rp = 0; rp < IT; rp += 2) {
        const int orow = rp + half;
        const int grr  = tile_r0 + orow;
        const float fc = flood_count[(size_t)grr * WW + gc];
        const u64* p = plane[wv][orow];
        int cv = 0;
#pragma unroll
        for (int k = 0; k < 5; ++k)
            cv += (int)((p[2 + k] >> bit) & 1ull) << k;
        float3 o3;
        o3.x = (float)((p[0] >> bit) & 1ull);
        o3.y = (float)((p[1] >> bit) & 1ull);
        o3.z = (float)cv + fc;
        *(float3*)(out + ((size_t)grr * WW + gc) * 3) = o3;
    }
}

extern "C" void kernel_launch(void* const* d_in, const int* in_sizes, int n_in,
                              void* d_out, int out_size, void* d_ws, size_t ws_size,
                              hipStream_t stream) {
    const float* flood_input = (const float*)d_in[0];  // [4096][4096][2]
    const float* flood_cnt   = (const float*)d_in[1];  // [4096][4096]
    float* out = (float*)d_out;                        // [4096][4096][3]

    u64* occP = (u64*)d_ws;                            // 2 MiB
    u64* flP  = occP + (size_t)HH * WPR;               // 2 MiB

    pack_kernel<<<dim3(HH), dim3(256), 0, stream>>>(flood_input, occP, flP);

    dim3 grid(WW / (4 * IT), HH / IT);                 // 32 x 128 = 4096 blocks
    flood_kernel<<<grid, dim3(256), 0, stream>>>(occP, flP, flood_cnt, out);
}

// Round 2
// 354.265 us; speedup vs baseline: 1.1714x; 1.1714x over previous
//
#include <hip/hip_runtime.h>

// FloodPath R5: R4's wave-autonomous register dilation + packed float4 output.
//   K1 (pack): unchanged — stream float2 [H][W][2] -> occ/flood bit planes.
//   K2 (flood): 64x64 halo'd window per wave in registers (lane=row, u64=cols),
//     16 shfl-based dilation steps, bit-sliced counters. Output stage REWRITTEN:
//     R4's float3 (12B/lane) stores caused 1.6x HBM write inflation
//     (WRITE_SIZE 315MB vs 196MB ideal). Now: per row-pair, lanes compute 4
//     consecutive pixels (48B), stage in LDS (3KB/wave), read back linearly,
//     store 3x dwordx4 per pair — every store instruction is contiguous and
//     covers full 128B lines.

typedef unsigned long long u64;

#define HH 4096
#define WW 4096
#define WPR 64            // u64 words per image row
#define NSTEPS 16
#define HALO 16
#define IT 32             // interior tile side per wave (64x64 window)

// ---------------- Kernel 1: bitpack ----------------
__global__ __launch_bounds__(256) void pack_kernel(
    const float* __restrict__ flood_input,
    u64* __restrict__ occP, u64* __restrict__ flP)
{
    const int lane = threadIdx.x & 63;
    const int wv   = threadIdx.x >> 6;
    const int r    = blockIdx.x;                  // one image row per block
#pragma unroll
    for (int b = 0; b < 2; ++b) {
        float vx[8], vy[8];
#pragma unroll
        for (int j = 0; j < 8; ++j) {
            const int w = wv * 16 + b * 8 + j;
            const float2 v = *(const float2*)(flood_input +
                                ((size_t)r * WW + (w << 6) + lane) * 2);
            vx[j] = v.x; vy[j] = v.y;
        }
#pragma unroll
        for (int j = 0; j < 8; ++j) {
            const int w = wv * 16 + b * 8 + j;
            const u64 om = __ballot(vx[j] > 0.5f);
            const u64 fm = __ballot(vy[j] > 0.5f);
            if (lane == 0) {
                occP[(size_t)r * WPR + w] = om;
                flP [(size_t)r * WPR + w] = fm;
            }
        }
    }
}

// ---------------- Kernel 2: flood + count + output ----------------
__global__ __launch_bounds__(256, 8) void flood_kernel(
    const u64* __restrict__ occP, const u64* __restrict__ flP,
    const float* __restrict__ flood_count,
    float* __restrict__ out)
{
    // [wave][interior row][occ, f, c0..c4] — 7168 B
    __shared__ u64 plane[4][IT][7];
    // per-wave packed output staging: 2 rows x 128 px x 3 ch = 3 KB/wave
    __shared__ float out2[4][2 * 128 * 3];

    const int tid  = threadIdx.x;
    const int lane = tid & 63;
    const int wv   = tid >> 6;

    const int tile_r0 = blockIdx.y * IT;                 // 0..4064
    const int tile_c0 = blockIdx.x * (4 * IT) + wv * IT; // grid.x = 32
    const int bc0    = blockIdx.x * (4 * IT);            // block col start

    // ---- Stage window: rows tile_r0-16+lane, cols tile_c0-16 .. +47.
    const int gr  = tile_r0 - HALO + lane;
    const bool rin = (gr >= 0) & (gr < HH);
    const int s   = tile_c0 - HALO;              // >= -16
    const int q0  = ((s + 64) >> 6) - 1;         // floor(s/64)
    const int sh  = s - (q0 << 6);               // 16 or 48

    const size_t base = (size_t)(rin ? gr : 0) * WPR;
    const int qa = min(max(q0, 0), WPR - 1);
    const int qb = min(max(q0 + 1, 0), WPR - 1);
    u64 o0 = occP[base + qa], o1 = occP[base + qb];
    u64 f0 = flP [base + qa], f1 = flP [base + qb];
    const bool va = rin & (q0 >= 0);
    const bool vb = rin & (q0 + 1 < WPR);
    if (!va) { o0 = ~0ull; f0 = 0ull; }          // OOB => wall, no flood
    if (!vb) { o1 = ~0ull; f1 = 0ull; }
    const u64 occ = (o0 >> sh) | (sh ? (o1 << (64 - sh)) : 0ull);
    u64       f   = (f0 >> sh) | (sh ? (f1 << (64 - sh)) : 0ull);

    // ---- 16 dilation steps, fully in registers. No barriers.
    const u64 nocc = ~occ;
    u64 c0 = 0, c1 = 0, c2 = 0, c3 = 0, c4 = 0;
#pragma unroll
    for (int it = 0; it < NSTEPS; ++it) {
        u64 up = __shfl_up(f, 1);
        u64 dn = __shfl_down(f, 1);
        if (lane == 0)  up = 0ull;
        if (lane == 63) dn = 0ull;
        f = nocc & (f | (f << 1) | (f >> 1) | up | dn);
        u64 c = f, t;
        t = c0; c0 = t ^ c; c = t & c;
        t = c1; c1 = t ^ c; c = t & c;
        t = c2; c2 = t ^ c; c = t & c;
        t = c3; c3 = t ^ c; c = t & c;
        c4 ^= c;                                 // max 16: no carry out
    }

    // ---- Transpose interior rows through LDS.
    if (lane >= HALO && lane < HALO + IT) {
        u64* p = plane[wv][lane - HALO];
        p[0] = occ; p[1] = f;
        p[2] = c0; p[3] = c1; p[4] = c2; p[5] = c3; p[6] = c4;
    }
    __syncthreads();

    // ---- Output: per wave, 8 interior rows = 4 row-pairs. For each pair:
    //   compute: lane -> 4 consecutive pixels (half-wave per row), 12 floats,
    //   stage contiguously in LDS, then 3 packed dwordx4 stores per lane.
    const int half = lane >> 5;                  // 0 or 1
    const int l32  = lane & 31;
    for (int t = 0; t < 4; ++t) {
        const int rA   = wv * 8 + 2 * t;         // pair's first interior row
        const int irow = rA + half;              // this lane's interior row
        const int grr  = tile_r0 + irow;
        const int col0 = l32 * 4;                // block-local col of 4 pixels

        const float4 fc4 = *(const float4*)(flood_count +
                                (size_t)grr * WW + bc0 + col0);
        const int sw   = col0 >> 5;              // source wave for these cols
        const u64* p   = plane[sw][irow];
        const u64 ow = p[0], fw = p[1];
        const u64 k0 = p[2], k1 = p[3], k2 = p[4], k3 = p[5], k4 = p[6];
        const int bit0 = HALO + (col0 & 31);

        float v[12];
        const float fcv[4] = { fc4.x, fc4.y, fc4.z, fc4.w };
#pragma unroll
        for (int j = 0; j < 4; ++j) {
            const int bit = bit0 + j;
            int cv = (int)((k0 >> bit) & 1ull)
                   + ((int)((k1 >> bit) & 1ull) << 1)
                   + ((int)((k2 >> bit) & 1ull) << 2)
                   + ((int)((k3 >> bit) & 1ull) << 3)
                   + ((int)((k4 >> bit) & 1ull) << 4);
            v[j * 3 + 0] = (float)((ow >> bit) & 1ull);
            v[j * 3 + 1] = (float)((fw >> bit) & 1ull);
            v[j * 3 + 2] = (float)cv + fcv[j];
        }
        // stage: byte offset = half*1536 + l32*48 (16B aligned, lane-linear)
        float* dst = &out2[wv][half * 384 + l32 * 12];
        *(float4*)(dst + 0) = make_float4(v[0], v[1], v[2],  v[3]);
        *(float4*)(dst + 4) = make_float4(v[4], v[5], v[6],  v[7]);
        *(float4*)(dst + 8) = make_float4(v[8], v[9], v[10], v[11]);

        __syncthreads();   // uniform across waves; write->read visibility

        // read back linearly, store packed dwordx4 (contiguous per instr)
        const float* src = &out2[wv][0];
#pragma unroll
        for (int st = 0; st < 3; ++st) {
            const int L   = st * 256 + lane * 4;   // float idx in 768-float pair
            const int row = (L >= 384) ? 1 : 0;    // 384 floats per row chunk
            const int off = L - row * 384;
            const float4 q = *(const float4*)(src + L);
            *(float4*)(out + ((size_t)(tile_r0 + rA + row) * WW + bc0) * 3 + off) = q;
        }
    }
}

extern "C" void kernel_launch(void* const* d_in, const int* in_sizes, int n_in,
                              void* d_out, int out_size, void* d_ws, size_t ws_size,
                              hipStream_t stream) {
    const float* flood_input = (const float*)d_in[0];  // [4096][4096][2]
    const float* flood_cnt   = (const float*)d_in[1];  // [4096][4096]
    float* out = (float*)d_out;                        // [4096][4096][3]

    u64* occP = (u64*)d_ws;                            // 2 MiB
    u64* flP  = occP + (size_t)HH * WPR;               // 2 MiB

    pack_kernel<<<dim3(HH), dim3(256), 0, stream>>>(flood_input, occP, flP);

    dim3 grid(WW / (4 * IT), HH / IT);                 // 32 x 128 = 4096 blocks
    flood_kernel<<<grid, dim3(256), 0, stream>>>(occP, flP, flood_cnt, out);
}